// Round 8
// baseline (172.329 us; speedup 1.0000x reference)
//
#include <hip/hip_runtime.h>

#define NN 2000

typedef _Float16 halfx8 __attribute__((ext_vector_type(8)));
typedef float floatx4 __attribute__((ext_vector_type(4)));

// lgkm-only barrier: LDS visibility without draining vmcnt (global loads stay
// in flight across phase boundaries). "memory" clobber pins compiler ordering.
#define LBAR() asm volatile("s_waitcnt lgkmcnt(0)\n\ts_barrier" ::: "memory")

// f32 -> OCP fp8 e4m3 (gfx950 HW convert; same format the fp8 MFMA consumes)
__device__ __forceinline__ unsigned char to_fp8(float v) {
    return (unsigned char)(__builtin_amdgcn_cvt_pk_fp8_f32(v, 0.f, 0, false) & 0xff);
}

// ---------------------------------------------------------------------------
// Kernel 1: sorted neighbor lists. All 32 chunk-loads prefetched before the
// ballot scan.
// ---------------------------------------------------------------------------
__global__ void build_nbrs_k(const float* __restrict__ adj,
                             int* __restrict__ nbrs) {
    int i = blockIdx.x;
    int lane = threadIdx.x;
    const float* row = adj + (size_t)i * NN;
    float v[32];
#pragma unroll
    for (int c = 0; c < 32; ++c) {
        int col = c * 64 + lane;
        v[c] = (col < NN) ? row[col] : 0.0f;
    }
    int base = 0;
#pragma unroll
    for (int c = 0; c < 32; ++c) {
        bool p = v[c] > 0.5f;
        unsigned long long mask = __ballot(p);
        if (p) {
            int pos = base + __popcll(mask & ((1ull << lane) - 1ull));
            nbrs[i * 16 + pos] = c * 64 + lane;
        }
        base += __popcll(mask);
    }
}

// ---------------------------------------------------------------------------
// Kernel 2: per-(i,m) maps + packed aux descriptor.
//   map8[i][m][a] = p : nbrs[j][p]==nbrs[i][a] (or -1), j=nbrs[i][m]
//   imp8[i][m][p] = a (inverse, or -1)
//   aux = { j,  a1|pa1<<8|a2<<16|pa2<<24,  vm|pmm<<16|ms<<24, 0 }
// ---------------------------------------------------------------------------
__global__ void build_map_k(const int* __restrict__ nbrs,
                            signed char* __restrict__ map8,
                            signed char* __restrict__ imp8,
                            int4* __restrict__ aux) {
    int idx = blockIdx.x * blockDim.x + threadIdx.x;  // (i,m)
    if (idx >= NN * 16) return;
    int i = idx >> 4;
    int m = idx & 15;
    int j = nbrs[idx];
    const int4* pi = (const int4*)(nbrs + (size_t)i * 16);
    const int4* pj = (const int4*)(nbrs + (size_t)j * 16);
    int4 A = pi[0], Bq = pi[1], C = pi[2], D = pi[3];
    int4 E = pj[0], F = pj[1], G = pj[2], H = pj[3];
    int ni[16] = {A.x,A.y,A.z,A.w, Bq.x,Bq.y,Bq.z,Bq.w, C.x,C.y,C.z,C.w, D.x,D.y,D.z,D.w};
    int nj[16] = {E.x,E.y,E.z,E.w, F.x,F.y,F.z,F.w, G.x,G.y,G.z,G.w, H.x,H.y,H.z,H.w};

    int mp[16];
    unsigned long long lo = 0, hi = 0;
#pragma unroll
    for (int a = 0; a < 16; ++a) {
        int r = -1;
#pragma unroll
        for (int p = 0; p < 16; ++p)
            if (nj[p] == ni[a]) r = p;
        mp[a] = r;
        unsigned long long b = (unsigned long long)(r & 0xff);
        if (a < 8) lo |= b << (8 * a); else hi |= b << (8 * (a - 8));
    }
    uint4 pk;
    pk.x = (unsigned)lo; pk.y = (unsigned)(lo >> 32);
    pk.z = (unsigned)hi; pk.w = (unsigned)(hi >> 32);
    *(uint4*)(map8 + ((size_t)idx << 4)) = pk;
    lo = 0; hi = 0;
#pragma unroll
    for (int p = 0; p < 16; ++p) {
        int r = -1;
#pragma unroll
        for (int a = 0; a < 16; ++a)
            if (ni[a] == nj[p]) r = a;
        unsigned long long b = (unsigned long long)(r & 0xff);
        if (p < 8) lo |= b << (8 * p); else hi |= b << (8 * (p - 8));
    }
    pk.x = (unsigned)lo; pk.y = (unsigned)(lo >> 32);
    pk.z = (unsigned)hi; pk.w = (unsigned)(hi >> 32);
    *(uint4*)(imp8 + ((size_t)idx << 4)) = pk;

    unsigned vm = 0;
    int a1 = -1, a2 = -1, pa1 = 0, pa2 = 0;
#pragma unroll
    for (int a = 0; a < 16; ++a) {
        if (mp[a] >= 0) {
            vm |= (1u << a);
            if (a1 < 0)      { a1 = a; pa1 = mp[a]; }
            else if (a2 < 0) { a2 = a; pa2 = mp[a]; }
        }
    }
    int ms = 0;
#pragma unroll
    for (int a = 0; a < 16; ++a)
        if (ni[a] == i) ms = a;
    int4 av;
    av.x = j;
    av.y = (a1 & 0xff) | ((pa1 & 0xff) << 8) | ((a2 & 0xff) << 16) | ((pa2 & 0xff) << 24);
    av.z = (int)(vm | ((unsigned)(mp[m] & 0xff) << 16) | ((unsigned)(ms & 0xff) << 24));
    av.w = 0;
    aux[idx] = av;
}

// ---------------------------------------------------------------------------
// Kernel 3: pack W1,W2 into MFMA B-fragments, once per launch.
// PRE chunks (maps, fp8 e4m3): c0=(blk2|blk4) c1=(blk6|blk8) c2=(blk10|-)
//   for ACC1; c3=(3|5) c4=(7|9) c5=(11|-) for ACC2.  (k<16 -> first blk)
// POST chunks (S0/V, f16): d0=(blk0|blk12) d1=(blk14|blk16) ACC1;
//   d2=(1|13) d3=(15|17) ACC2.
// B-frag: lane L holds B[k=(L>>4)*8+j][n=L&15].
// ---------------------------------------------------------------------------
__global__ void prep_w_k(const float* __restrict__ W1,
                         const float* __restrict__ W2,
                         unsigned char* __restrict__ Wpk8,
                         _Float16* __restrict__ Wpk16) {
    int idx = blockIdx.x * blockDim.x + threadIdx.x;
    if (idx >= 10240) return;
    if (idx < 6144) {            // fp8 PRE: [2][6][64][8] bytes
        int stage = idx / 3072;
        int r = idx % 3072;
        int c = r / 512;
        int r2 = r % 512;
        int L = r2 >> 3, jj = r2 & 7;
        int q = L >> 4, h = L & 15;
        int k = q * 8 + jj;
        const int bA[6] = {2, 6, 10, 3, 7, 11};
        const int bB[6] = {4, 8, -1, 5, 9, -1};
        int tb = (k < 16) ? bA[c] : bB[c];
        int ci = k & 15;
        const float* W = stage ? W2 : W1;
        float val = (tb < 0) ? 0.f : W[h * 288 + tb * 16 + ci];
        Wpk8[idx] = to_fp8(val);
    } else {                     // f16 POST: [2][4][64][8] halves
        int id2 = idx - 6144;
        int stage = id2 / 2048;
        int r = id2 % 2048;
        int c = r / 512;
        int r2 = r % 512;
        int L = r2 >> 3, jj = r2 & 7;
        int q = L >> 4, h = L & 15;
        int k = q * 8 + jj;
        const int bA[4] = {0, 14, 1, 15};
        const int bB[4] = {12, 16, 13, 17};
        int tb = (k < 16) ? bA[c] : bB[c];
        int ci = k & 15;
        const float* W = stage ? W2 : W1;
        float val = W[h * 288 + tb * 16 + ci];
        Wpk16[id2] = (_Float16)val;
    }
}

// ---------------------------------------------------------------------------
// Kernel 4: one CCN step per node. chi = partial permutation =>
// T[m,a,b,c] = Fp[j, mp(a), mp(b), c].
//   S0 f32 stride-16 (self plain + sparse LDS atomics), maps A2/A4/A6/A8/A10
//   in **fp8** (wave-private rows), V0 plain, V1/V2 f32 atomics.
// 18-block contraction: PRE chunks on mfma_f32_16x16x32_fp8_fp8 before
// barrier B, POST chunks (S0/V) on f16 MFMA after — both chain into the same
// fp32 accumulators (C/D layout is dtype-independent on gfx950).
// LDS total = 16384 + 20480 + 4096 = 40960 B exactly -> 4 blocks/CU.
// ---------------------------------------------------------------------------
template <int DIAG>
__global__ __launch_bounds__(256, 4)
void step_k(const float* __restrict__ Fp,    // (N,16,16,16) or null (DIAG)
            const float* __restrict__ Xp,    // (N,16) when DIAG
            const unsigned char* __restrict__ Wpk8s,  // this stage's fp8 B-frags (3072 B)
            const _Float16* __restrict__ Wpk16s,      // this stage's f16 B-frags (2048 h)
            const float* __restrict__ bias,  // (16)
            const signed char* __restrict__ map8,
            const signed char* __restrict__ imp8,
            const int4* __restrict__ auxp,
            float* __restrict__ Fout,        // (N,16,16,16) or null
            float* __restrict__ gp0,         // [16][2048] h-major F0 partials (DIAG)
            float* __restrict__ gp) {        // [16][8192] h-major per-wave partials
    __shared__ __attribute__((aligned(16))) float S0[16][16][16];            // 16384
    __shared__ __attribute__((aligned(16))) unsigned char MAP8[5][16][16][16];// 20480 (reused as P2 post-B)
    __shared__ __attribute__((aligned(16))) float V0f[16][16];               // 1024
    __shared__ __attribute__((aligned(16))) float V1f[16][16];               // 1024
    __shared__ __attribute__((aligned(16))) float V2f[16][16];               // 1024
    __shared__ __attribute__((aligned(16))) float S1f[16][16];               // 1024: self rowsums / Xs
    // total 40960 B -> 4 blocks/CU

    const int i = blockIdx.x;
    const int t = threadIdx.x;
    const int u = t >> 4;        // group id (= m / tile row)
    const int l = t & 15;        // lane in group (= channel)
    const int lane = t & 63, q = lane >> 4, h = lane & 15, wv = t >> 6;

    // ---- prologue: issue independent global loads ----
    int4 av = auxp[i * 16 + u];
    uint4 imv = *(const uint4*)(imp8 + ((size_t)(i * 16 + u) << 4));
    float bv = bias[l];
    const int j = av.x;
    const int a1 = (int)(signed char)(av.y & 0xff);
    const int pa1 = (av.y >> 8) & 0xff;
    const int a2 = (int)(signed char)((av.y >> 16) & 0xff);
    const int pa2 = (av.y >> 24) & 0xff;
    const unsigned vm = (unsigned)(av.z & 0xffff);
    const int pmm = (av.z >> 16) & 0xff;
    const int ms = (av.z >> 24) & 0xff;

    float frow[16], fcol[16], xv = 0.f;
    if (DIAG) {
        xv = Xp[(size_t)j * 16 + l];
    } else {
        const float* Fi = Fp + (size_t)i * 4096;
#pragma unroll
        for (int b = 0; b < 16; ++b) frow[b] = Fi[(u * 16 + b) * 16 + l];
#pragma unroll
        for (int a = 0; a < 16; ++a) fcol[a] = Fi[(a * 16 + u) * 16 + l];
    }

    // gather prefetch: rows for first (and second) valid a
    float R1[16], R2[16];
    if (!DIAG && u != ms) {
        const float* P1 = Fp + (((size_t)j * 256 + pa1 * 16) * 16) + l;
#pragma unroll
        for (int p = 0; p < 16; ++p) R1[p] = P1[p * 16];
        if (a2 >= 0) {
            const float* P2 = Fp + (((size_t)j * 256 + pa2 * 16) * 16) + l;
#pragma unroll
            for (int p = 0; p < 16; ++p) R2[p] = P2[p * 16];
        }
    }
    // B-frags: packed weights, issued pre-barrier -> stay in flight
    long Bf8[6];
    {
        const long* Wq8 = (const long*)Wpk8s;
#pragma unroll
        for (int c = 0; c < 6; ++c) Bf8[c] = Wq8[c * 64 + lane];
    }
    halfx8 Bf16[4];
    {
        const halfx8* Wq16 = (const halfx8*)Wpk16s;
#pragma unroll
        for (int c = 0; c < 4; ++c) Bf16[c] = Wq16[c * 64 + lane];
    }

    // ---- phase 1: zero MAP rows (m != ms), self-loop stores ----
    if (u != ms) {
        uint4 z = {0u, 0u, 0u, 0u};
#pragma unroll
        for (int k = 0; k < 5; ++k)
            *(uint4*)&MAP8[k][u][l][0] = z;   // fp8 row = 16 B = one uint4
    }
    if (DIAG) {
        S1f[u][l] = xv;                 // Xs staging
        V1f[u][l] = xv;
        V2f[u][l] = xv;
#pragma unroll
        for (int b = 0; b < 16; ++b) S0[u][b][l] = (b == u) ? xv : 0.f;
        unsigned char x8 = to_fp8(xv);
        MAP8[0][ms][u][l] = x8;                     // A2[ms][b=u]
        MAP8[1][ms][u][l] = x8;                     // A4[ms][a=u]
        unsigned char dz = (u == ms) ? x8 : (unsigned char)0;
        MAP8[2][ms][u][l] = dz;                     // A6[ms][b=u]
        MAP8[3][ms][u][l] = dz;                     // A8[ms][a=u]
        MAP8[4][ms][u][l] = x8;                     // A10[ms][y=u]
    } else {
        float s2 = 0.f, a10 = 0.f, a8 = 0.f;
#pragma unroll
        for (int b = 0; b < 16; ++b) {
            float v = frow[b];
            s2 += v;
            S0[u][b][l] = v;
            if (b == u)  a10 = v;       // Fi[u][u]
            if (b == ms) a8 = v;        // Fi[u][ms]
        }
        float s1 = 0.f, a6 = 0.f;
#pragma unroll
        for (int a = 0; a < 16; ++a) {
            float v = fcol[a];
            s1 += v;
            if (a == ms) a6 = v;        // Fi[ms][u]
        }
        S1f[u][l] = s2;                 // self rowsums (V0[ms] source)
        V1f[u][l] = s2;
        V2f[u][l] = s1;
        MAP8[0][ms][u][l] = to_fp8(s1);    // A2[ms][b=u]
        MAP8[1][ms][u][l] = to_fp8(s2);    // A4[ms][a=u]
        MAP8[2][ms][u][l] = to_fp8(a6);    // A6[ms][b=u]
        MAP8[3][ms][u][l] = to_fp8(a8);    // A8[ms][a=u]
        MAP8[4][ms][u][l] = to_fp8(a10);   // A10[ms][u]
    }
    LBAR();   // A

    // ---- phase 2: sparse m (group u = m); group ms does V0[ms] ----
    if (u != ms) {
        const int m = u;
        float v0acc = 0.f;
        if (DIAG) {
#pragma unroll
            for (int a = 0; a < 16; ++a) {
                if ((vm >> a) & 1u) {
                    float v = S1f[a][l];     // X[nbrs[i,a], l]
                    v0acc += v;
                    atomicAdd(&S0[a][a][l], v);
                    atomicAdd(&V1f[a][l], v);
                    atomicAdd(&V2f[a][l], v);
                    unsigned char v8 = to_fp8(v);
                    MAP8[0][m][a][l] = v8;
                    MAP8[1][m][a][l] = v8;
                    MAP8[4][m][a][l] = v8;
                    if (a == m) { MAP8[2][m][m][l] = v8; MAP8[3][m][m][l] = v8; }
                }
            }
        } else {
            float colacc[16];
#pragma unroll
            for (int p = 0; p < 16; ++p) colacc[p] = 0.f;
            auto process = [&](int a, int pa, const float (&vr)[16]) {
                float rowacc = 0.f, a8v = 0.f, a10v = 0.f;
                const bool am = (a == m);
#pragma unroll
                for (int p = 0; p < 16; ++p) {
                    float v = vr[p];
                    if (p == pmm) a8v = v;       // Fj[pa][pmm]
                    if (p == pa)  a10v = v;      // Fj[pa][pa]
                    unsigned dw = (p < 4) ? imv.x : ((p < 8) ? imv.y : ((p < 12) ? imv.z : imv.w));
                    int b = (int)(signed char)((dw >> (8 * (p & 3))) & 0xffu);
                    if (b >= 0) {
                        rowacc += v;
                        colacc[p] += v;
                        atomicAdd(&S0[a][b][l], v);
                        atomicAdd(&V2f[b][l], v);
                        if (am) MAP8[2][m][b][l] = to_fp8(v);  // A6[m][b]
                    }
                }
                v0acc += rowacc;
                atomicAdd(&V1f[a][l], rowacc);
                MAP8[1][m][a][l] = to_fp8(rowacc);   // A4
                MAP8[3][m][a][l] = to_fp8(a8v);      // A8
                MAP8[4][m][a][l] = to_fp8(a10v);     // A10
            };
            process(a1, pa1, R1);
            if (a2 >= 0) process(a2, pa2, R2);
            unsigned rm = vm & ~(1u << a1);
            if (a2 >= 0) rm &= ~(1u << a2);
            if (rm) {                    // rare tail (>2 overlaps): lazy map load
                uint4 mpq = *(const uint4*)(map8 + ((size_t)(i * 16 + u) << 4));
                do {
                    int a = __builtin_ctz(rm); rm &= rm - 1;
                    unsigned dw = (a & 8) ? ((a & 4) ? mpq.w : mpq.z) : ((a & 4) ? mpq.y : mpq.x);
                    int pa = (int)(signed char)((dw >> (8 * (a & 3))) & 0xffu);
                    float RT[16];
                    const float* P3 = Fp + (((size_t)j * 256 + pa * 16) * 16) + l;
#pragma unroll
                    for (int p = 0; p < 16; ++p) RT[p] = P3[p * 16];
                    process(a, pa, RT);
                } while (rm);
            }
#pragma unroll
            for (int p = 0; p < 16; ++p) {
                unsigned dw = (p < 4) ? imv.x : ((p < 8) ? imv.y : ((p < 12) ? imv.z : imv.w));
                int b = (int)(signed char)((dw >> (8 * (p & 3))) & 0xffu);
                if (b >= 0) MAP8[0][m][b][l] = to_fp8(colacc[p]);  // A2
            }
        }
        V0f[m][l] = v0acc;
    } else {
        float v0s = 0.f;
#pragma unroll
        for (int b = 0; b < 16; ++b) v0s += S1f[b][l];
        V0f[ms][l] = v0s;
        if (DIAG) gp0[l * 2048 + i] = v0s;   // h-major F0 g-partial
    }

    // ---- PRE-MFMAs (fp8): map chunks, wave-private rows -> no barrier ----
    floatx4 acc1[4], acc2[4];
#pragma unroll
    for (int tt = 0; tt < 4; ++tt) {
        acc1[tt] = (floatx4){0.f, 0.f, 0.f, 0.f};
        acc2[tt] = (floatx4){0.f, 0.f, 0.f, 0.f};
    }
    const int wbase = wv * 4;
    {
        const int off8 = (q & 1) * 8;
        const unsigned char* mA = (q < 2) ? &MAP8[0][0][0][0] : &MAP8[1][0][0][0];
        const unsigned char* mB = (q < 2) ? &MAP8[2][0][0][0] : &MAP8[3][0][0][0];
        const unsigned char* mC = &MAP8[4][0][0][0];
#pragma unroll
        for (int tt = 0; tt < 4; ++tt) {
            const int x = wbase + tt;
            const int base = x * 256 + h * 16 + off8;
            long f0 = *(const long*)(mA + base);
            long f1 = *(const long*)(mB + base);
            long f2 = (q < 2) ? *(const long*)(mC + base) : 0L;
            acc1[tt] = __builtin_amdgcn_mfma_f32_16x16x32_fp8_fp8(f0, Bf8[0], acc1[tt], 0, 0, 0);
            acc1[tt] = __builtin_amdgcn_mfma_f32_16x16x32_fp8_fp8(f1, Bf8[1], acc1[tt], 0, 0, 0);
            acc1[tt] = __builtin_amdgcn_mfma_f32_16x16x32_fp8_fp8(f2, Bf8[2], acc1[tt], 0, 0, 0);
            acc2[tt] = __builtin_amdgcn_mfma_f32_16x16x32_fp8_fp8(f0, Bf8[3], acc2[tt], 0, 0, 0);
            acc2[tt] = __builtin_amdgcn_mfma_f32_16x16x32_fp8_fp8(f1, Bf8[4], acc2[tt], 0, 0, 0);
            acc2[tt] = __builtin_amdgcn_mfma_f32_16x16x32_fp8_fp8(f2, Bf8[5], acc2[tt], 0, 0, 0);
        }
    }
    LBAR();   // B: S0 / V1 / V2 atomics complete; MAP8 globally dead after this

    // ---- POST-MFMAs (f16): S0 + V chunks ----
    auto cvt8a = [](const float* p) -> halfx8 {  // 16B-aligned f32 -> f16x8
        float4 va = *(const float4*)p, vb = *(const float4*)(p + 4);
        halfx8 r;
        r[0] = (_Float16)va.x; r[1] = (_Float16)va.y; r[2] = (_Float16)va.z; r[3] = (_Float16)va.w;
        r[4] = (_Float16)vb.x; r[5] = (_Float16)vb.y; r[6] = (_Float16)vb.z; r[7] = (_Float16)vb.w;
        return r;
    };
#pragma unroll
    for (int tt = 0; tt < 4; ++tt) {
        const int x = wbase + tt;
        halfx8 p3, p4;
        if (q < 2) {
            p3 = cvt8a(&S0[x][h][q * 8]);                // S0 (blk0/1)
            p4 = cvt8a(&V1f[x][q * 8]);                  // V1 (blk14/15)
        } else {
            const int c0 = (q - 2) * 8;
            p3 = cvt8a(&V0f[x][c0]);                     // V0 (blk12/13)
            p4 = cvt8a(&V2f[x][c0]);                     // V2 (blk16/17)
        }
        acc1[tt] = __builtin_amdgcn_mfma_f32_16x16x32_f16(p3, Bf16[0], acc1[tt], 0, 0, 0);
        acc1[tt] = __builtin_amdgcn_mfma_f32_16x16x32_f16(p4, Bf16[1], acc1[tt], 0, 0, 0);
        acc2[tt] = __builtin_amdgcn_mfma_f32_16x16x32_f16(p3, Bf16[2], acc2[tt], 0, 0, 0);
        acc2[tt] = __builtin_amdgcn_mfma_f32_16x16x32_f16(p4, Bf16[3], acc2[tt], 0, 0, 0);
    }

    // ---- transpose ACC2 through the (dead) MAP8 region; writes need no
    //      barrier (all MAP8 reads completed before barrier B) ----
    float* P2f = (float*)&MAP8[0][0][0][0];   // [r][s][h] stride 17 (17408 B <= 20480)
#pragma unroll
    for (int tt = 0; tt < 4; ++tt) {
        const int x = wbase + tt;
#pragma unroll
        for (int r = 0; r < 4; ++r)
            P2f[(x * 16 + (q * 4 + r)) * 17 + h] = acc2[tt][r];
    }
    LBAR();   // C

    // ---- epilogue: combine, relu, store; per-wave g-partials ----
    float gpart = 0.f;
#pragma unroll
    for (int tt = 0; tt < 4; ++tt) {
        const int x = wbase + tt;
#pragma unroll
        for (int r = 0; r < 4; ++r) {
            const int y = q * 4 + r;
            float val = acc1[tt][r] + P2f[(y * 16 + x) * 17 + h] + bv;
            val = fmaxf(val, 0.f);
            gpart += val;
            if (Fout) Fout[(size_t)i * 4096 + (x * 16 + y) * 16 + h] = val;
        }
    }
    gpart += __shfl_xor(gpart, 16, 64);
    gpart += __shfl_xor(gpart, 32, 64);
    if (lane < 16) gp[h * 8192 + i * 4 + wv] = gpart;   // h-major
}

// ---------------------------------------------------------------------------
// Kernel 5: reduce h-major partials -> gsum[48]. Fully coalesced float4 reads.
// parts layout: slot0 [16][2048] | slot1 [16][8192] | slot2 [16][8192]
// ---------------------------------------------------------------------------
__global__ void reduce_g_k(const float* __restrict__ parts,
                           float* __restrict__ gsum) {
    int r = blockIdx.x;           // 0..47
    const float* p;
    int cnt4;
    if (r < 16)      { p = parts + r * 2048;                    cnt4 = 500;  }  // 2000 floats
    else if (r < 32) { p = parts + 32768 + (r - 16) * 8192;     cnt4 = 2000; }  // 8000 floats
    else             { p = parts + 163840 + (r - 32) * 8192;    cnt4 = 2000; }
    const float4* p4 = (const float4*)p;
    int t = threadIdx.x;
    float s = 0.f;
    for (int n = t; n < cnt4; n += 256) {
        float4 v = p4[n];
        s += v.x + v.y + v.z + v.w;
    }
#pragma unroll
    for (int off = 32; off > 0; off >>= 1) s += __shfl_xor(s, off, 64);
    __shared__ float wsum[4];
    if ((t & 63) == 0) wsum[t >> 6] = s;
    __syncthreads();
    if (t == 0) gsum[r] = wsum[0] + wsum[1] + wsum[2] + wsum[3];
}

// ---------------------------------------------------------------------------
// Kernel 6: out = g . fc_w + fc_b
// ---------------------------------------------------------------------------
__global__ void finalize_k(const float* __restrict__ gsum,
                           const float* __restrict__ fcw,
                           const float* __restrict__ fcb,
                           float* __restrict__ out) {
    int t = threadIdx.x;
    float v = (t < 48) ? gsum[t] * fcw[t] : 0.f;
#pragma unroll
    for (int off = 32; off > 0; off >>= 1) v += __shfl_xor(v, off, 64);
    if (t == 0) out[0] = v + fcb[0];
}

extern "C" void kernel_launch(void* const* d_in, const int* in_sizes, int n_in,
                              void* d_out, int out_size, void* d_ws, size_t ws_size,
                              hipStream_t stream) {
    const float* X   = (const float*)d_in[0];
    const float* adj = (const float*)d_in[1];
    const float* W1  = (const float*)d_in[2];
    const float* b1  = (const float*)d_in[3];
    const float* W2  = (const float*)d_in[4];
    const float* b2  = (const float*)d_in[5];
    const float* fcw = (const float*)d_in[6];
    const float* fcb = (const float*)d_in[7];
    float* out = (float*)d_out;
    char* ws = (char*)d_ws;

    // workspace layout (16B-aligned):
    float*         gsum  = (float*)(ws + 0);               // 192 B
    int*           nbrs  = (int*)(ws + 1024);              // 128000 B
    signed char*   map8  = (signed char*)(ws + 129280);    // 512000 B
    signed char*   imp8  = (signed char*)(ws + 641280);    // 512000 B
    int4*          aux   = (int4*)(ws + 1153280);          // 512000 B
    float*         parts = (float*)(ws + 1665280);         // 1179648 B
    unsigned char* Wpk8  = (unsigned char*)(ws + 2844928); // 6144 B
    _Float16*      Wpk16 = (_Float16*)(ws + 2851072);      // 8192 B
    float*         F1    = (float*)(ws + 2859264);         // 32768000 B (~35.6 MB total)

    build_nbrs_k<<<NN, 64, 0, stream>>>(adj, nbrs);
    build_map_k<<<(NN * 16 + 255) / 256, 256, 0, stream>>>(nbrs, map8, imp8, aux);
    prep_w_k<<<40, 256, 0, stream>>>(W1, W2, Wpk8, Wpk16);
    // parts: slot0 = F0 [16][2048] | slot1 = F1 [16][8192] | slot2 = F2 [16][8192]
    step_k<1><<<NN, 256, 0, stream>>>(nullptr, X, Wpk8, Wpk16, b1, map8, imp8, aux, F1,
                                      parts, parts + 32768);
    step_k<0><<<NN, 256, 0, stream>>>(F1, X, Wpk8 + 3072, Wpk16 + 2048, b2, map8, imp8, aux,
                                      nullptr, nullptr, parts + 163840);
    reduce_g_k<<<48, 256, 0, stream>>>(parts, gsum);
    finalize_k<<<1, 64, 0, stream>>>(gsum, fcw, fcb, out);
}

// Round 9
// 151.357 us; speedup vs baseline: 1.1386x; 1.1386x over previous
//
#include <hip/hip_runtime.h>

#define NN 2000

typedef _Float16 halfx8 __attribute__((ext_vector_type(8)));
typedef float floatx4 __attribute__((ext_vector_type(4)));

// lgkm-only barrier: LDS visibility without draining vmcnt (global loads stay
// in flight across phase boundaries). "memory" clobber pins compiler ordering.
#define LBAR() asm volatile("s_waitcnt lgkmcnt(0)\n\ts_barrier" ::: "memory")

// f32 -> OCP fp8 e4m3 (gfx950 HW convert; same format the fp8 MFMA consumes)
__device__ __forceinline__ unsigned char to_fp8(float v) {
    return (unsigned char)(__builtin_amdgcn_cvt_pk_fp8_f32(v, 0.f, 0, false) & 0xff);
}

// ---------------------------------------------------------------------------
// Kernel 1: sorted neighbor lists. All 32 chunk-loads prefetched before the
// ballot scan.
// ---------------------------------------------------------------------------
__global__ void build_nbrs_k(const float* __restrict__ adj,
                             int* __restrict__ nbrs) {
    int i = blockIdx.x;
    int lane = threadIdx.x;
    const float* row = adj + (size_t)i * NN;
    float v[32];
#pragma unroll
    for (int c = 0; c < 32; ++c) {
        int col = c * 64 + lane;
        v[c] = (col < NN) ? row[col] : 0.0f;
    }
    int base = 0;
#pragma unroll
    for (int c = 0; c < 32; ++c) {
        bool p = v[c] > 0.5f;
        unsigned long long mask = __ballot(p);
        if (p) {
            int pos = base + __popcll(mask & ((1ull << lane) - 1ull));
            nbrs[i * 16 + pos] = c * 64 + lane;
        }
        base += __popcll(mask);
    }
}

// ---------------------------------------------------------------------------
// Kernel 2: per-(i,m) maps + packed aux descriptor.
//   map8[i][m][a] = p : nbrs[j][p]==nbrs[i][a] (or -1), j=nbrs[i][m]
//   imp8[i][m][p] = a (inverse, or -1)
//   aux = { j,  a1|pa1<<8|a2<<16|pa2<<24,  vm|pmm<<16|ms<<24, 0 }
// ---------------------------------------------------------------------------
__global__ void build_map_k(const int* __restrict__ nbrs,
                            signed char* __restrict__ map8,
                            signed char* __restrict__ imp8,
                            int4* __restrict__ aux) {
    int idx = blockIdx.x * blockDim.x + threadIdx.x;  // (i,m)
    if (idx >= NN * 16) return;
    int i = idx >> 4;
    int m = idx & 15;
    int j = nbrs[idx];
    const int4* pi = (const int4*)(nbrs + (size_t)i * 16);
    const int4* pj = (const int4*)(nbrs + (size_t)j * 16);
    int4 A = pi[0], Bq = pi[1], C = pi[2], D = pi[3];
    int4 E = pj[0], F = pj[1], G = pj[2], H = pj[3];
    int ni[16] = {A.x,A.y,A.z,A.w, Bq.x,Bq.y,Bq.z,Bq.w, C.x,C.y,C.z,C.w, D.x,D.y,D.z,D.w};
    int nj[16] = {E.x,E.y,E.z,E.w, F.x,F.y,F.z,F.w, G.x,G.y,G.z,G.w, H.x,H.y,H.z,H.w};

    int mp[16];
    unsigned long long lo = 0, hi = 0;
#pragma unroll
    for (int a = 0; a < 16; ++a) {
        int r = -1;
#pragma unroll
        for (int p = 0; p < 16; ++p)
            if (nj[p] == ni[a]) r = p;
        mp[a] = r;
        unsigned long long b = (unsigned long long)(r & 0xff);
        if (a < 8) lo |= b << (8 * a); else hi |= b << (8 * (a - 8));
    }
    uint4 pk;
    pk.x = (unsigned)lo; pk.y = (unsigned)(lo >> 32);
    pk.z = (unsigned)hi; pk.w = (unsigned)(hi >> 32);
    *(uint4*)(map8 + ((size_t)idx << 4)) = pk;
    lo = 0; hi = 0;
#pragma unroll
    for (int p = 0; p < 16; ++p) {
        int r = -1;
#pragma unroll
        for (int a = 0; a < 16; ++a)
            if (ni[a] == nj[p]) r = a;
        unsigned long long b = (unsigned long long)(r & 0xff);
        if (p < 8) lo |= b << (8 * p); else hi |= b << (8 * (p - 8));
    }
    pk.x = (unsigned)lo; pk.y = (unsigned)(lo >> 32);
    pk.z = (unsigned)hi; pk.w = (unsigned)(hi >> 32);
    *(uint4*)(imp8 + ((size_t)idx << 4)) = pk;

    unsigned vm = 0;
    int a1 = -1, a2 = -1, pa1 = 0, pa2 = 0;
#pragma unroll
    for (int a = 0; a < 16; ++a) {
        if (mp[a] >= 0) {
            vm |= (1u << a);
            if (a1 < 0)      { a1 = a; pa1 = mp[a]; }
            else if (a2 < 0) { a2 = a; pa2 = mp[a]; }
        }
    }
    int ms = 0;
#pragma unroll
    for (int a = 0; a < 16; ++a)
        if (ni[a] == i) ms = a;
    int4 av;
    av.x = j;
    av.y = (a1 & 0xff) | ((pa1 & 0xff) << 8) | ((a2 & 0xff) << 16) | ((pa2 & 0xff) << 24);
    av.z = (int)(vm | ((unsigned)(mp[m] & 0xff) << 16) | ((unsigned)(ms & 0xff) << 24));
    av.w = 0;
    aux[idx] = av;
}

// ---------------------------------------------------------------------------
// Kernel 3: pack W1,W2 into MFMA B-fragments, once per launch.
// PRE chunks (maps, fp8 e4m3): c0=(blk2|blk4) c1=(blk6|blk8) c2=(blk10|-)
//   for ACC1; c3=(3|5) c4=(7|9) c5=(11|-) for ACC2.  (k<16 -> first blk)
// POST chunks (S0/V, f16): d0=(blk0|blk12) d1=(blk14|blk16) ACC1;
//   d2=(1|13) d3=(15|17) ACC2.
// B-frag: lane L holds B[k=(L>>4)*8+j][n=L&15].
// ---------------------------------------------------------------------------
__global__ void prep_w_k(const float* __restrict__ W1,
                         const float* __restrict__ W2,
                         unsigned char* __restrict__ Wpk8,
                         _Float16* __restrict__ Wpk16) {
    int idx = blockIdx.x * blockDim.x + threadIdx.x;
    if (idx >= 10240) return;
    if (idx < 6144) {            // fp8 PRE: [2][6][64][8] bytes
        int stage = idx / 3072;
        int r = idx % 3072;
        int c = r / 512;
        int r2 = r % 512;
        int L = r2 >> 3, jj = r2 & 7;
        int q = L >> 4, h = L & 15;
        int k = q * 8 + jj;
        const int bA[6] = {2, 6, 10, 3, 7, 11};
        const int bB[6] = {4, 8, -1, 5, 9, -1};
        int tb = (k < 16) ? bA[c] : bB[c];
        int ci = k & 15;
        const float* W = stage ? W2 : W1;
        float val = (tb < 0) ? 0.f : W[h * 288 + tb * 16 + ci];
        Wpk8[idx] = to_fp8(val);
    } else {                     // f16 POST: [2][4][64][8] halves
        int id2 = idx - 6144;
        int stage = id2 / 2048;
        int r = id2 % 2048;
        int c = r / 512;
        int r2 = r % 512;
        int L = r2 >> 3, jj = r2 & 7;
        int q = L >> 4, h = L & 15;
        int k = q * 8 + jj;
        const int bA[4] = {0, 14, 1, 15};
        const int bB[4] = {12, 16, 13, 17};
        int tb = (k < 16) ? bA[c] : bB[c];
        int ci = k & 15;
        const float* W = stage ? W2 : W1;
        float val = W[h * 288 + tb * 16 + ci];
        Wpk16[id2] = (_Float16)val;
    }
}

// ---------------------------------------------------------------------------
// Kernel 4: one CCN step per node. chi = partial permutation =>
// T[m,a,b,c] = Fp[j, mp(a), mp(b), c].
//   S0 f32 stride-16 (self plain + sparse LDS atomics), maps A2/A4/A6/A8/A10
//   in fp8 (wave-private rows), V0 plain, V1/V2 f32 atomics.
// 18-block contraction: PRE chunks on mfma_f32_16x16x32_fp8_fp8 before
// barrier B, POST chunks (S0/V) on f16 MFMA after — both chain into the same
// fp32 accumulators (C/D layout is dtype-independent on gfx950).
// LDS total = 40960 B -> 4 blocks/CU.
// __launch_bounds__(256,3): R8's (256,4) forced VGPR=64 -> ~170 B/thread
// scratch spills (85 MB WRITE_SIZE). Bound 3 lets the natural ~88-VGPR
// allocation through (no spills); runtime still fits 4 blocks/CU since
// 4 waves/EU x ~88 VGPR < 512-reg file.
// ---------------------------------------------------------------------------
template <int DIAG>
__global__ __launch_bounds__(256, 3)
void step_k(const float* __restrict__ Fp,    // (N,16,16,16) or null (DIAG)
            const float* __restrict__ Xp,    // (N,16) when DIAG
            const unsigned char* __restrict__ Wpk8s,  // this stage's fp8 B-frags (3072 B)
            const _Float16* __restrict__ Wpk16s,      // this stage's f16 B-frags (2048 h)
            const float* __restrict__ bias,  // (16)
            const signed char* __restrict__ map8,
            const signed char* __restrict__ imp8,
            const int4* __restrict__ auxp,
            float* __restrict__ Fout,        // (N,16,16,16) or null
            float* __restrict__ gp0,         // [16][2048] h-major F0 partials (DIAG)
            float* __restrict__ gp) {        // [16][8192] h-major per-wave partials
    __shared__ __attribute__((aligned(16))) float S0[16][16][16];            // 16384
    __shared__ __attribute__((aligned(16))) unsigned char MAP8[5][16][16][16];// 20480 (reused as P2 post-B)
    __shared__ __attribute__((aligned(16))) float V0f[16][16];               // 1024
    __shared__ __attribute__((aligned(16))) float V1f[16][16];               // 1024
    __shared__ __attribute__((aligned(16))) float V2f[16][16];               // 1024
    __shared__ __attribute__((aligned(16))) float S1f[16][16];               // 1024: self rowsums / Xs
    // total 40960 B -> 4 blocks/CU

    const int i = blockIdx.x;
    const int t = threadIdx.x;
    const int u = t >> 4;        // group id (= m / tile row)
    const int l = t & 15;        // lane in group (= channel)
    const int lane = t & 63, q = lane >> 4, h = lane & 15, wv = t >> 6;

    // ---- prologue: issue independent global loads ----
    int4 av = auxp[i * 16 + u];
    uint4 imv = *(const uint4*)(imp8 + ((size_t)(i * 16 + u) << 4));
    float bv = bias[l];
    const int j = av.x;
    const int a1 = (int)(signed char)(av.y & 0xff);
    const int pa1 = (av.y >> 8) & 0xff;
    const int a2 = (int)(signed char)((av.y >> 16) & 0xff);
    const int pa2 = (av.y >> 24) & 0xff;
    const unsigned vm = (unsigned)(av.z & 0xffff);
    const int pmm = (av.z >> 16) & 0xff;
    const int ms = (av.z >> 24) & 0xff;

    float frow[16], fcol[16], xv = 0.f;
    if (DIAG) {
        xv = Xp[(size_t)j * 16 + l];
    } else {
        const float* Fi = Fp + (size_t)i * 4096;
#pragma unroll
        for (int b = 0; b < 16; ++b) frow[b] = Fi[(u * 16 + b) * 16 + l];
#pragma unroll
        for (int a = 0; a < 16; ++a) fcol[a] = Fi[(a * 16 + u) * 16 + l];
    }

    // gather prefetch: rows for first (and second) valid a
    float R1[16], R2[16];
    if (!DIAG && u != ms) {
        const float* P1 = Fp + (((size_t)j * 256 + pa1 * 16) * 16) + l;
#pragma unroll
        for (int p = 0; p < 16; ++p) R1[p] = P1[p * 16];
        if (a2 >= 0) {
            const float* P2 = Fp + (((size_t)j * 256 + pa2 * 16) * 16) + l;
#pragma unroll
            for (int p = 0; p < 16; ++p) R2[p] = P2[p * 16];
        }
    }
    // B-frags: packed weights, issued pre-barrier -> stay in flight
    long Bf8[6];
    {
        const long* Wq8 = (const long*)Wpk8s;
#pragma unroll
        for (int c = 0; c < 6; ++c) Bf8[c] = Wq8[c * 64 + lane];
    }
    halfx8 Bf16[4];
    {
        const halfx8* Wq16 = (const halfx8*)Wpk16s;
#pragma unroll
        for (int c = 0; c < 4; ++c) Bf16[c] = Wq16[c * 64 + lane];
    }

    // ---- phase 1: zero MAP rows (m != ms), self-loop stores ----
    if (u != ms) {
        uint4 z = {0u, 0u, 0u, 0u};
#pragma unroll
        for (int k = 0; k < 5; ++k)
            *(uint4*)&MAP8[k][u][l][0] = z;   // fp8 row = 16 B = one uint4
    }
    if (DIAG) {
        S1f[u][l] = xv;                 // Xs staging
        V1f[u][l] = xv;
        V2f[u][l] = xv;
#pragma unroll
        for (int b = 0; b < 16; ++b) S0[u][b][l] = (b == u) ? xv : 0.f;
        unsigned char x8 = to_fp8(xv);
        MAP8[0][ms][u][l] = x8;                     // A2[ms][b=u]
        MAP8[1][ms][u][l] = x8;                     // A4[ms][a=u]
        unsigned char dz = (u == ms) ? x8 : (unsigned char)0;
        MAP8[2][ms][u][l] = dz;                     // A6[ms][b=u]
        MAP8[3][ms][u][l] = dz;                     // A8[ms][a=u]
        MAP8[4][ms][u][l] = x8;                     // A10[ms][y=u]
    } else {
        float s2 = 0.f, a10 = 0.f, a8 = 0.f;
#pragma unroll
        for (int b = 0; b < 16; ++b) {
            float v = frow[b];
            s2 += v;
            S0[u][b][l] = v;
            if (b == u)  a10 = v;       // Fi[u][u]
            if (b == ms) a8 = v;        // Fi[u][ms]
        }
        float s1 = 0.f, a6 = 0.f;
#pragma unroll
        for (int a = 0; a < 16; ++a) {
            float v = fcol[a];
            s1 += v;
            if (a == ms) a6 = v;        // Fi[ms][u]
        }
        S1f[u][l] = s2;                 // self rowsums (V0[ms] source)
        V1f[u][l] = s2;
        V2f[u][l] = s1;
        MAP8[0][ms][u][l] = to_fp8(s1);    // A2[ms][b=u]
        MAP8[1][ms][u][l] = to_fp8(s2);    // A4[ms][a=u]
        MAP8[2][ms][u][l] = to_fp8(a6);    // A6[ms][b=u]
        MAP8[3][ms][u][l] = to_fp8(a8);    // A8[ms][a=u]
        MAP8[4][ms][u][l] = to_fp8(a10);   // A10[ms][u]
    }
    LBAR();   // A

    // ---- phase 2: sparse m (group u = m); group ms does V0[ms] ----
    if (u != ms) {
        const int m = u;
        float v0acc = 0.f;
        if (DIAG) {
#pragma unroll
            for (int a = 0; a < 16; ++a) {
                if ((vm >> a) & 1u) {
                    float v = S1f[a][l];     // X[nbrs[i,a], l]
                    v0acc += v;
                    atomicAdd(&S0[a][a][l], v);
                    atomicAdd(&V1f[a][l], v);
                    atomicAdd(&V2f[a][l], v);
                    unsigned char v8 = to_fp8(v);
                    MAP8[0][m][a][l] = v8;
                    MAP8[1][m][a][l] = v8;
                    MAP8[4][m][a][l] = v8;
                    if (a == m) { MAP8[2][m][m][l] = v8; MAP8[3][m][m][l] = v8; }
                }
            }
        } else {
            float colacc[16];
#pragma unroll
            for (int p = 0; p < 16; ++p) colacc[p] = 0.f;
            auto process = [&](int a, int pa, const float (&vr)[16]) {
                float rowacc = 0.f, a8v = 0.f, a10v = 0.f;
                const bool am = (a == m);
#pragma unroll
                for (int p = 0; p < 16; ++p) {
                    float v = vr[p];
                    if (p == pmm) a8v = v;       // Fj[pa][pmm]
                    if (p == pa)  a10v = v;      // Fj[pa][pa]
                    unsigned dw = (p < 4) ? imv.x : ((p < 8) ? imv.y : ((p < 12) ? imv.z : imv.w));
                    int b = (int)(signed char)((dw >> (8 * (p & 3))) & 0xffu);
                    if (b >= 0) {
                        rowacc += v;
                        colacc[p] += v;
                        atomicAdd(&S0[a][b][l], v);
                        atomicAdd(&V2f[b][l], v);
                        if (am) MAP8[2][m][b][l] = to_fp8(v);  // A6[m][b]
                    }
                }
                v0acc += rowacc;
                atomicAdd(&V1f[a][l], rowacc);
                MAP8[1][m][a][l] = to_fp8(rowacc);   // A4
                MAP8[3][m][a][l] = to_fp8(a8v);      // A8
                MAP8[4][m][a][l] = to_fp8(a10v);     // A10
            };
            process(a1, pa1, R1);
            if (a2 >= 0) process(a2, pa2, R2);
            unsigned rm = vm & ~(1u << a1);
            if (a2 >= 0) rm &= ~(1u << a2);
            if (rm) {                    // rare tail (>2 overlaps): lazy map load
                uint4 mpq = *(const uint4*)(map8 + ((size_t)(i * 16 + u) << 4));
                do {
                    int a = __builtin_ctz(rm); rm &= rm - 1;
                    unsigned dw = (a & 8) ? ((a & 4) ? mpq.w : mpq.z) : ((a & 4) ? mpq.y : mpq.x);
                    int pa = (int)(signed char)((dw >> (8 * (a & 3))) & 0xffu);
                    float RT[16];
                    const float* P3 = Fp + (((size_t)j * 256 + pa * 16) * 16) + l;
#pragma unroll
                    for (int p = 0; p < 16; ++p) RT[p] = P3[p * 16];
                    process(a, pa, RT);
                } while (rm);
            }
#pragma unroll
            for (int p = 0; p < 16; ++p) {
                unsigned dw = (p < 4) ? imv.x : ((p < 8) ? imv.y : ((p < 12) ? imv.z : imv.w));
                int b = (int)(signed char)((dw >> (8 * (p & 3))) & 0xffu);
                if (b >= 0) MAP8[0][m][b][l] = to_fp8(colacc[p]);  // A2
            }
        }
        V0f[m][l] = v0acc;
    } else {
        float v0s = 0.f;
#pragma unroll
        for (int b = 0; b < 16; ++b) v0s += S1f[b][l];
        V0f[ms][l] = v0s;
        if (DIAG) gp0[l * 2048 + i] = v0s;   // h-major F0 g-partial
    }

    // ---- PRE-MFMAs (fp8): map chunks, wave-private rows -> no barrier ----
    floatx4 acc1[4], acc2[4];
#pragma unroll
    for (int tt = 0; tt < 4; ++tt) {
        acc1[tt] = (floatx4){0.f, 0.f, 0.f, 0.f};
        acc2[tt] = (floatx4){0.f, 0.f, 0.f, 0.f};
    }
    const int wbase = wv * 4;
    {
        const int off8 = (q & 1) * 8;
        const unsigned char* mA = (q < 2) ? &MAP8[0][0][0][0] : &MAP8[1][0][0][0];
        const unsigned char* mB = (q < 2) ? &MAP8[2][0][0][0] : &MAP8[3][0][0][0];
        const unsigned char* mC = &MAP8[4][0][0][0];
#pragma unroll
        for (int tt = 0; tt < 4; ++tt) {
            const int x = wbase + tt;
            const int base = x * 256 + h * 16 + off8;
            long f0 = *(const long*)(mA + base);
            long f1 = *(const long*)(mB + base);
            long f2 = (q < 2) ? *(const long*)(mC + base) : 0L;
            acc1[tt] = __builtin_amdgcn_mfma_f32_16x16x32_fp8_fp8(f0, Bf8[0], acc1[tt], 0, 0, 0);
            acc1[tt] = __builtin_amdgcn_mfma_f32_16x16x32_fp8_fp8(f1, Bf8[1], acc1[tt], 0, 0, 0);
            acc1[tt] = __builtin_amdgcn_mfma_f32_16x16x32_fp8_fp8(f2, Bf8[2], acc1[tt], 0, 0, 0);
            acc2[tt] = __builtin_amdgcn_mfma_f32_16x16x32_fp8_fp8(f0, Bf8[3], acc2[tt], 0, 0, 0);
            acc2[tt] = __builtin_amdgcn_mfma_f32_16x16x32_fp8_fp8(f1, Bf8[4], acc2[tt], 0, 0, 0);
            acc2[tt] = __builtin_amdgcn_mfma_f32_16x16x32_fp8_fp8(f2, Bf8[5], acc2[tt], 0, 0, 0);
        }
    }
    LBAR();   // B: S0 / V1 / V2 atomics complete; MAP8 globally dead after this

    // ---- POST-MFMAs (f16): S0 + V chunks ----
    auto cvt8a = [](const float* p) -> halfx8 {  // 16B-aligned f32 -> f16x8
        float4 va = *(const float4*)p, vb = *(const float4*)(p + 4);
        halfx8 r;
        r[0] = (_Float16)va.x; r[1] = (_Float16)va.y; r[2] = (_Float16)va.z; r[3] = (_Float16)va.w;
        r[4] = (_Float16)vb.x; r[5] = (_Float16)vb.y; r[6] = (_Float16)vb.z; r[7] = (_Float16)vb.w;
        return r;
    };
#pragma unroll
    for (int tt = 0; tt < 4; ++tt) {
        const int x = wbase + tt;
        halfx8 p3, p4;
        if (q < 2) {
            p3 = cvt8a(&S0[x][h][q * 8]);                // S0 (blk0/1)
            p4 = cvt8a(&V1f[x][q * 8]);                  // V1 (blk14/15)
        } else {
            const int c0 = (q - 2) * 8;
            p3 = cvt8a(&V0f[x][c0]);                     // V0 (blk12/13)
            p4 = cvt8a(&V2f[x][c0]);                     // V2 (blk16/17)
        }
        acc1[tt] = __builtin_amdgcn_mfma_f32_16x16x32_f16(p3, Bf16[0], acc1[tt], 0, 0, 0);
        acc1[tt] = __builtin_amdgcn_mfma_f32_16x16x32_f16(p4, Bf16[1], acc1[tt], 0, 0, 0);
        acc2[tt] = __builtin_amdgcn_mfma_f32_16x16x32_f16(p3, Bf16[2], acc2[tt], 0, 0, 0);
        acc2[tt] = __builtin_amdgcn_mfma_f32_16x16x32_f16(p4, Bf16[3], acc2[tt], 0, 0, 0);
    }

    // ---- transpose ACC2 through the (dead) MAP8 region; writes need no
    //      barrier (all MAP8 reads completed before barrier B) ----
    float* P2f = (float*)&MAP8[0][0][0][0];   // [r][s][h] stride 17 (17408 B <= 20480)
#pragma unroll
    for (int tt = 0; tt < 4; ++tt) {
        const int x = wbase + tt;
#pragma unroll
        for (int r = 0; r < 4; ++r)
            P2f[(x * 16 + (q * 4 + r)) * 17 + h] = acc2[tt][r];
    }
    LBAR();   // C

    // ---- epilogue: combine, relu, store; per-wave g-partials ----
    float gpart = 0.f;
#pragma unroll
    for (int tt = 0; tt < 4; ++tt) {
        const int x = wbase + tt;
#pragma unroll
        for (int r = 0; r < 4; ++r) {
            const int y = q * 4 + r;
            float val = acc1[tt][r] + P2f[(y * 16 + x) * 17 + h] + bv;
            val = fmaxf(val, 0.f);
            gpart += val;
            if (Fout) Fout[(size_t)i * 4096 + (x * 16 + y) * 16 + h] = val;
        }
    }
    gpart += __shfl_xor(gpart, 16, 64);
    gpart += __shfl_xor(gpart, 32, 64);
    if (lane < 16) gp[h * 8192 + i * 4 + wv] = gpart;   // h-major
}

// ---------------------------------------------------------------------------
// Kernel 5: reduce h-major partials -> gsum[48]. Fully coalesced float4 reads.
// parts layout: slot0 [16][2048] | slot1 [16][8192] | slot2 [16][8192]
// ---------------------------------------------------------------------------
__global__ void reduce_g_k(const float* __restrict__ parts,
                           float* __restrict__ gsum) {
    int r = blockIdx.x;           // 0..47
    const float* p;
    int cnt4;
    if (r < 16)      { p = parts + r * 2048;                    cnt4 = 500;  }  // 2000 floats
    else if (r < 32) { p = parts + 32768 + (r - 16) * 8192;     cnt4 = 2000; }  // 8000 floats
    else             { p = parts + 163840 + (r - 32) * 8192;    cnt4 = 2000; }
    const float4* p4 = (const float4*)p;
    int t = threadIdx.x;
    float s = 0.f;
    for (int n = t; n < cnt4; n += 256) {
        float4 v = p4[n];
        s += v.x + v.y + v.z + v.w;
    }
#pragma unroll
    for (int off = 32; off > 0; off >>= 1) s += __shfl_xor(s, off, 64);
    __shared__ float wsum[4];
    if ((t & 63) == 0) wsum[t >> 6] = s;
    __syncthreads();
    if (t == 0) gsum[r] = wsum[0] + wsum[1] + wsum[2] + wsum[3];
}

// ---------------------------------------------------------------------------
// Kernel 6: out = g . fc_w + fc_b
// ---------------------------------------------------------------------------
__global__ void finalize_k(const float* __restrict__ gsum,
                           const float* __restrict__ fcw,
                           const float* __restrict__ fcb,
                           float* __restrict__ out) {
    int t = threadIdx.x;
    float v = (t < 48) ? gsum[t] * fcw[t] : 0.f;
#pragma unroll
    for (int off = 32; off > 0; off >>= 1) v += __shfl_xor(v, off, 64);
    if (t == 0) out[0] = v + fcb[0];
}

extern "C" void kernel_launch(void* const* d_in, const int* in_sizes, int n_in,
                              void* d_out, int out_size, void* d_ws, size_t ws_size,
                              hipStream_t stream) {
    const float* X   = (const float*)d_in[0];
    const float* adj = (const float*)d_in[1];
    const float* W1  = (const float*)d_in[2];
    const float* b1  = (const float*)d_in[3];
    const float* W2  = (const float*)d_in[4];
    const float* b2  = (const float*)d_in[5];
    const float* fcw = (const float*)d_in[6];
    const float* fcb = (const float*)d_in[7];
    float* out = (float*)d_out;
    char* ws = (char*)d_ws;

    // workspace layout (16B-aligned):
    float*         gsum  = (float*)(ws + 0);               // 192 B
    int*           nbrs  = (int*)(ws + 1024);              // 128000 B
    signed char*   map8  = (signed char*)(ws + 129280);    // 512000 B
    signed char*   imp8  = (signed char*)(ws + 641280);    // 512000 B
    int4*          aux   = (int4*)(ws + 1153280);          // 512000 B
    float*         parts = (float*)(ws + 1665280);         // 1179648 B
    unsigned char* Wpk8  = (unsigned char*)(ws + 2844928); // 6144 B
    _Float16*      Wpk16 = (_Float16*)(ws + 2851072);      // 8192 B
    float*         F1    = (float*)(ws + 2859264);         // 32768000 B (~35.6 MB total)

    build_nbrs_k<<<NN, 64, 0, stream>>>(adj, nbrs);
    build_map_k<<<(NN * 16 + 255) / 256, 256, 0, stream>>>(nbrs, map8, imp8, aux);
    prep_w_k<<<40, 256, 0, stream>>>(W1, W2, Wpk8, Wpk16);
    // parts: slot0 = F0 [16][2048] | slot1 = F1 [16][8192] | slot2 = F2 [16][8192]
    step_k<1><<<NN, 256, 0, stream>>>(nullptr, X, Wpk8, Wpk16, b1, map8, imp8, aux, F1,
                                      parts, parts + 32768);
    step_k<0><<<NN, 256, 0, stream>>>(F1, X, Wpk8 + 3072, Wpk16 + 2048, b2, map8, imp8, aux,
                                      nullptr, nullptr, parts + 163840);
    reduce_g_k<<<48, 256, 0, stream>>>(parts, gsum);
    finalize_k<<<1, 64, 0, stream>>>(gsum, fcw, fcb, out);
}